// Round 2
// 10177.675 us; speedup vs baseline: 1.0484x; 1.0484x over previous
//
#include <hip/hip_runtime.h>
#include <hip/hip_cooperative_groups.h>

namespace cg = cooperative_groups;

#define SEQ   512
#define BATCH 64
#define DIM   1024
#define HID   1024
#define GCOLS 4096   // 4 gates * HID (column-permuted: col' = (c>>2)*16 + g*4 + (c&3))
#define NBLK  64     // recurrence blocks; each owns 16 hidden units (64 gate cols)

typedef float  floatx4 __attribute__((ext_vector_type(4)));
typedef short  shortx8 __attribute__((ext_vector_type(8)));
union ABFrag  { uint4 u; shortx8 s; };
union ABFrag2 { unsigned long long q[2]; uint4 u; shortx8 s; };

// ---------- bf16 helpers (raw ushort, RNE) ----------
__device__ __forceinline__ unsigned short f2bf(float f) {
  union { float f; unsigned int u; } v; v.f = f;
  unsigned int r = v.u + 0x7FFFu + ((v.u >> 16) & 1u);
  return (unsigned short)(r >> 16);
}
__device__ __forceinline__ float bf2f(unsigned short u) {
  union { unsigned int u; float f; } v; v.u = ((unsigned int)u) << 16;
  return v.f;
}

__device__ __forceinline__ float sigm(float x) {
  return 1.f / (1.f + __expf(-x));
}
__device__ __forceinline__ float tanh_s(float x) {
  float a = fabsf(x);
  float e = __expf(-2.f * a);
  float r = (1.f - e) / (1.f + e);
  return x < 0.f ? -r : r;
}

// ---------- Phase 1: G[(t*64+b)][(c>>2)*16 + g*4 + (c&3)] = x@Wx_g + bx_g + bh_g (bf16) ----------
// (verbatim — proven)
__global__ __launch_bounds__(256) void gemm_x(
    const float* __restrict__ X,
    const float* __restrict__ W0, const float* __restrict__ W1,
    const float* __restrict__ W2, const float* __restrict__ W3,
    const float* __restrict__ bx0, const float* __restrict__ bx1,
    const float* __restrict__ bx2, const float* __restrict__ bx3,
    const float* __restrict__ bh0, const float* __restrict__ bh1,
    const float* __restrict__ bh2, const float* __restrict__ bh3,
    unsigned short* __restrict__ G)
{
  __shared__ __align__(16) float As[8][132];
  __shared__ __align__(16) float Bs[8][132];

  const int tid = threadIdx.x;
  const int g   = blockIdx.z;
  const float* W  = (g==0) ? W0  : (g==1) ? W1  : (g==2) ? W2  : W3;
  const float* bx = (g==0) ? bx0 : (g==1) ? bx1 : (g==2) ? bx2 : bx3;
  const float* bh = (g==0) ? bh0 : (g==1) ? bh1 : (g==2) ? bh2 : bh3;
  const int n0 = blockIdx.x * 128;
  const int m0 = blockIdx.y * 128;
  const int tx = tid & 15, ty = tid >> 4;

  const int am = tid >> 1;
  const int ak = (tid & 1) * 4;
  const int bk = tid >> 5;
  const int bn = (tid & 31) * 4;

  float acc[8][8];
#pragma unroll
  for (int i = 0; i < 8; ++i)
#pragma unroll
    for (int j = 0; j < 8; ++j) acc[i][j] = 0.f;

  for (int k0 = 0; k0 < DIM; k0 += 8) {
    float4 av = *(const float4*)(X + (size_t)(m0 + am) * DIM + k0 + ak);
    float4 bv = *(const float4*)(W + (size_t)(k0 + bk) * HID + n0 + bn);
    __syncthreads();
    As[ak+0][am] = av.x; As[ak+1][am] = av.y; As[ak+2][am] = av.z; As[ak+3][am] = av.w;
    *(float4*)&Bs[bk][bn] = bv;
    __syncthreads();
#pragma unroll
    for (int kk = 0; kk < 8; ++kk) {
      float4 a0 = *(const float4*)&As[kk][ty*8];
      float4 a1 = *(const float4*)&As[kk][ty*8+4];
      float4 b0 = *(const float4*)&Bs[kk][tx*8];
      float4 b1 = *(const float4*)&Bs[kk][tx*8+4];
      float ar[8] = {a0.x,a0.y,a0.z,a0.w,a1.x,a1.y,a1.z,a1.w};
      float br[8] = {b0.x,b0.y,b0.z,b0.w,b1.x,b1.y,b1.z,b1.w};
#pragma unroll
      for (int i = 0; i < 8; ++i)
#pragma unroll
        for (int j = 0; j < 8; ++j)
          acc[i][j] = __builtin_fmaf(ar[i], br[j], acc[i][j]);
    }
  }

  const int c0 = n0 + tx*8;
  float bias[8];
#pragma unroll
  for (int j = 0; j < 8; ++j) bias[j] = bx[c0 + j] + bh[c0 + j];

  const size_t cbase = (size_t)(c0 >> 2) * 16 + g * 4;
#pragma unroll
  for (int i = 0; i < 8; ++i) {
    size_t rowbase = (size_t)(m0 + ty*8 + i) * GCOLS;
    ushort4 lo, hi;
    lo.x = f2bf(acc[i][0] + bias[0]); lo.y = f2bf(acc[i][1] + bias[1]);
    lo.z = f2bf(acc[i][2] + bias[2]); lo.w = f2bf(acc[i][3] + bias[3]);
    hi.x = f2bf(acc[i][4] + bias[4]); hi.y = f2bf(acc[i][5] + bias[5]);
    hi.z = f2bf(acc[i][6] + bias[6]); hi.w = f2bf(acc[i][7] + bias[7]);
    *(ushort4*)(G + rowbase + cbase)      = lo;
    *(ushort4*)(G + rowbase + cbase + 16) = hi;
  }
}

// ---------- Phase 2: 64 blocks x 256 threads, block owns 16 hidden units ----------
// Wave wv computes C[16 batches x 64 gate-cols]: 4 B-tiles share each A-frag
// (4x A-reuse vs round-0 16x16 tiles -> h broadcast 32MB -> 8MB per step).
// Wh slice (1024 x 64 cols bf16 = 128KB) LDS-resident. Barrier: 64 arrivals.
// PROTOCOL = round-0 proven: h staged in LDS, published by WAVE 0 ONLY,
// tid0 drains wave-0 stores with explicit s_waitcnt vmcnt(0) before arrive.
__global__ __launch_bounds__(256) void lstm_rec(
    const unsigned short* __restrict__ G,       // [512*64][4096] bf16, permuted
    const float* __restrict__ Whf, const float* __restrict__ Whi,
    const float* __restrict__ Who, const float* __restrict__ Whc,
    unsigned short* __restrict__ hbuf,          // bf16 [2][64][1024] ping-pong
    unsigned long long* __restrict__ barCnt,    // 1 counter
    float* __restrict__ out)                    // h_seq | h | c (fp32)
{
  // [kt 32][ct 4][lane 64][8 bf16] = 128 KB B-fragments
  __shared__ __align__(16) unsigned short Wswz[32 * 4 * 64 * 8];
  __shared__ float pre[64][65];                  // preacts [batch][colInBlock]
  __shared__ __align__(8) unsigned short hout[64][16]; // h staging [batch][unit]

  const int tid  = threadIdx.x;
  const int bid  = blockIdx.x;
  const int j0   = bid * 16;      // first hidden unit owned by this block
  const int lane = tid & 63;
  const int wv   = tid >> 6;

  // One-time: swizzle 64 Wh gate-columns into MFMA B-fragment order.
  // idx = kt*256 + ct*64 + l ; B-frag: lane l holds B[k=kt*32+(l>>4)*8+j][col16=l&15]
  for (int idx = tid; idx < 32 * 4 * 64; idx += 256) {
    int kt = idx >> 8, ct = (idx >> 6) & 3, l = idx & 63;
    int ci = l & 15, g = ci >> 2, u = ci & 3;
    const float* W = (g==0) ? Whf : (g==1) ? Whi : (g==2) ? Who : Whc;
    int col = j0 + ct * 4 + u;
    int kbase = kt * 32 + (l >> 4) * 8;
    unsigned short* dst = &Wswz[idx * 8];
#pragma unroll
    for (int j = 0; j < 8; ++j)
      dst[j] = f2bf(W[(size_t)(kbase + j) * HID + col]);
  }
  // One-time: zero h0 stripe (slot 0): 64 rows x 4 u64 -> exactly 256 threads
  {
    int row = tid >> 2, part = tid & 3;
    unsigned long long* dst =
        (unsigned long long*)(hbuf + (size_t)row * HID + j0 + part * 4);
    __hip_atomic_store(dst, 0ull, __ATOMIC_RELAXED, __HIP_MEMORY_SCOPE_AGENT);
  }
  if (bid == 0 && tid == 0)
    __hip_atomic_store(barCnt, 0ull, __ATOMIC_RELAXED, __HIP_MEMORY_SCOPE_AGENT);

  cg::grid_group grid = cg::this_grid();
  grid.sync();   // ONLY init sync: Wswz is block-local; h0 + counter global

  const int ar = lane & 15;      // A row in tile / C col
  const int aq = lane >> 4;      // quad
  const int mrow = wv * 16 + ar; // batch row this lane loads for A
  const int pb = tid & 63;       // pointwise: batch
  const int pg = tid >> 6;       // pointwise: unit group (4 units, == B-tile ct)
  float c_reg[4] = {0.f, 0.f, 0.f, 0.f};
  unsigned long long tgt = 0;

  for (int t = 0; t < SEQ; ++t) {
    const unsigned short* hp = hbuf + (t & 1) * (BATCH * HID);
    const unsigned short* Gt = G + (size_t)t * (BATCH * GCOLS);

    // prefetch this thread's own 32B G slice (16 contiguous permuted cols:
    // units pg*4..pg*4+3 x 4 gates); consumed after the MFMA loop
    const unsigned short* gp = Gt + (size_t)pb * GCOLS + bid * 64 + pg * 16;
    uint4 gva = *(const uint4*)gp;
    uint4 gvb = *(const uint4*)(gp + 8);

    // A-fragments straight from coherent h buffer (round-0 interleaved form):
    // 4 x u64 agent loads per 2 K-tiles, pipelined against 8 MFMAs.
    const unsigned long long* ap =
        (const unsigned long long*)(hp + (size_t)mrow * HID);
    floatx4 acc[4][2];
#pragma unroll
    for (int ct = 0; ct < 4; ++ct) {
      acc[ct][0] = (floatx4){0.f, 0.f, 0.f, 0.f};
      acc[ct][1] = (floatx4){0.f, 0.f, 0.f, 0.f};
    }
#pragma unroll 4
    for (int kt = 0; kt < 32; kt += 2) {
      ABFrag2 a0, a1;
      a0.q[0] = __hip_atomic_load(ap + 8*kt + 2*aq,     __ATOMIC_RELAXED, __HIP_MEMORY_SCOPE_AGENT);
      a0.q[1] = __hip_atomic_load(ap + 8*kt + 2*aq + 1, __ATOMIC_RELAXED, __HIP_MEMORY_SCOPE_AGENT);
      a1.q[0] = __hip_atomic_load(ap + 8*kt + 8 + 2*aq, __ATOMIC_RELAXED, __HIP_MEMORY_SCOPE_AGENT);
      a1.q[1] = __hip_atomic_load(ap + 8*kt + 9 + 2*aq, __ATOMIC_RELAXED, __HIP_MEMORY_SCOPE_AGENT);
#pragma unroll
      for (int ct = 0; ct < 4; ++ct) {
        ABFrag b0, b1;
        b0.u = *(const uint4*)&Wswz[((kt * 4 + ct) * 64 + lane) * 8];
        b1.u = *(const uint4*)&Wswz[(((kt + 1) * 4 + ct) * 64 + lane) * 8];
        acc[ct][0] = __builtin_amdgcn_mfma_f32_16x16x32_bf16(a0.s, b0.s, acc[ct][0], 0, 0, 0);
        acc[ct][1] = __builtin_amdgcn_mfma_f32_16x16x32_bf16(a1.s, b1.s, acc[ct][1], 0, 0, 0);
      }
    }

    // C layout: col = lane&15, row = (lane>>4)*4 + reg ; row here = batch-in-wave
#pragma unroll
    for (int ct = 0; ct < 4; ++ct)
#pragma unroll
      for (int r = 0; r < 4; ++r)
        pre[wv * 16 + aq * 4 + r][ct * 16 + ar] = acc[ct][0][r] + acc[ct][1][r];
    __syncthreads();

    // pointwise: thread (pb, pg) owns batch pb, units j0+pg*4 .. +3
    {
      union { uint4 u; unsigned short s[8]; } ga, gb;
      ga.u = gva; gb.u = gvb;
      float hq[4];
#pragma unroll
      for (int uu = 0; uu < 4; ++uu) {
        float pf = pre[pb][pg*16 + uu]      + bf2f(ga.s[uu]);      // gate f (g=0)
        float pi = pre[pb][pg*16 + 4 + uu]  + bf2f(ga.s[4 + uu]);  // gate i (g=1)
        float po = pre[pb][pg*16 + 8 + uu]  + bf2f(gb.s[uu]);      // gate o (g=2)
        float pc = pre[pb][pg*16 + 12 + uu] + bf2f(gb.s[4 + uu]);  // gate c (g=3)
        float f  = sigm(pf);
        float i2 = sigm(pi);
        float o  = sigm(po);
        float gg = tanh_s(pc);
        c_reg[uu] = f * c_reg[uu] + i2 * gg;
        hq[uu] = o * tanh_s(c_reg[uu]);
      }
      // stage h in LDS (publish below is wave-0-only, proven protocol)
      union { unsigned long long q; unsigned short s[4]; } hv;
#pragma unroll
      for (int uu = 0; uu < 4; ++uu) hv.s[uu] = f2bf(hq[uu]);
      *(unsigned long long*)&hout[pb][pg * 4] = hv.q;

      float4 ov = {hq[0], hq[1], hq[2], hq[3]};
      *(float4*)(out + ((size_t)t * BATCH + pb) * HID + j0 + pg * 4) = ov;
      if (t == SEQ - 1) {
        *(float4*)(out + (size_t)SEQ * BATCH * HID + (size_t)pb * HID + j0 + pg * 4) = ov;
        float4 cv = {c_reg[0], c_reg[1], c_reg[2], c_reg[3]};
        *(float4*)(out + (size_t)SEQ * BATCH * HID + (size_t)BATCH * HID
                   + (size_t)pb * HID + j0 + pg * 4) = cv;
      }
    }
    __syncthreads();

    // publish h_new: WAVE 0 ONLY, 4 u64 coherent stores per batch row
    if (tid < 64) {
      unsigned long long* dstrow = (unsigned long long*)
          (hbuf + ((t + 1) & 1) * (BATCH * HID) + (size_t)tid * HID + j0);
#pragma unroll
      for (int p = 0; p < 4; ++p) {
        unsigned long long pv = *(const unsigned long long*)&hout[tid][p * 4];
        __hip_atomic_store(dstrow + p, pv, __ATOMIC_RELAXED, __HIP_MEMORY_SCOPE_AGENT);
      }
    }
    // flush-free barrier: drain wave-0 stores to coherence point, arrive, spin
    tgt += NBLK;
    if (tid == 0) {
      asm volatile("s_waitcnt vmcnt(0)" ::: "memory");
      __hip_atomic_fetch_add(barCnt, 1ull, __ATOMIC_RELAXED, __HIP_MEMORY_SCOPE_AGENT);
      while (__hip_atomic_load(barCnt, __ATOMIC_RELAXED, __HIP_MEMORY_SCOPE_AGENT)
             < tgt)
        __builtin_amdgcn_s_sleep(1);
    }
    __syncthreads();  // releases block; next step's A-loads read L3-fresh h
  }
}

extern "C" void kernel_launch(void* const* d_in, const int* in_sizes, int n_in,
                              void* d_out, int out_size, void* d_ws, size_t ws_size,
                              hipStream_t stream)
{
  const float* x   = (const float*)d_in[0];
  const float* Wxf = (const float*)d_in[1];
  const float* bxf = (const float*)d_in[2];
  const float* Wxi = (const float*)d_in[3];
  const float* bxi = (const float*)d_in[4];
  const float* Wxo = (const float*)d_in[5];
  const float* bxo = (const float*)d_in[6];
  const float* Wxc = (const float*)d_in[7];
  const float* bxc = (const float*)d_in[8];
  const float* Whf = (const float*)d_in[9];
  const float* bhf = (const float*)d_in[10];
  const float* Whi = (const float*)d_in[11];
  const float* bhi = (const float*)d_in[12];
  const float* Who = (const float*)d_in[13];
  const float* bho = (const float*)d_in[14];
  const float* Whc = (const float*)d_in[15];
  const float* bhc = (const float*)d_in[16];

  // ws: G bf16 (256MB) | hbuf bf16 [2][64][1024] (256KB) | barrier counter
  const size_t G_BYTES = (size_t)SEQ * BATCH * GCOLS * sizeof(unsigned short);
  const size_t H_BYTES = (size_t)2 * BATCH * HID * sizeof(unsigned short);
  unsigned short* G    = (unsigned short*)d_ws;
  unsigned short* hbuf = (unsigned short*)((char*)d_ws + G_BYTES);
  unsigned long long* barCnt = (unsigned long long*)((char*)d_ws + G_BYTES + H_BYTES);
  float* out = (float*)d_out;

  dim3 g1(8, 256, 4);
  hipLaunchKernelGGL(gemm_x, g1, dim3(256), 0, stream,
                     x, Wxf, Wxi, Wxo, Wxc,
                     bxf, bxi, bxo, bxc,
                     bhf, bhi, bho, bhc, G);

  void* args[] = { (void*)&G, (void*)&Whf, (void*)&Whi, (void*)&Who, (void*)&Whc,
                   (void*)&hbuf, (void*)&barCnt, (void*)&out };
  hipLaunchCooperativeKernel((void*)lstm_rec, dim3(NBLK), dim3(256), args, 0, stream);
}

// Round 4
// 7247.198 us; speedup vs baseline: 1.4723x; 1.4044x over previous
//
#include <hip/hip_runtime.h>
#include <hip/hip_cooperative_groups.h>

namespace cg = cooperative_groups;

#define SEQ   512
#define BATCH 64
#define DIM   1024
#define HID   1024
#define GCOLS 4096   // 4 gates * HID (column-permuted: col' = (c>>2)*16 + g*4 + (c&3))
#define NBLK  64     // recurrence blocks; each owns 16 hidden units (64 gate cols)

typedef float  floatx4 __attribute__((ext_vector_type(4)));
typedef short  shortx8 __attribute__((ext_vector_type(8)));
union ABFrag  { uint4 u; shortx8 s; };
union ABFrag2 { unsigned long long q[2]; uint4 u; shortx8 s; };

// ---------- bf16 helpers (raw ushort, RNE) ----------
__device__ __forceinline__ unsigned short f2bf(float f) {
  union { float f; unsigned int u; } v; v.f = f;
  unsigned int r = v.u + 0x7FFFu + ((v.u >> 16) & 1u);
  return (unsigned short)(r >> 16);
}
__device__ __forceinline__ float bf2f(unsigned short u) {
  union { unsigned int u; float f; } v; v.u = ((unsigned int)u) << 16;
  return v.f;
}
// pack 2 fp32 -> 2 bf16 (RNE), single VALU op
__device__ __forceinline__ unsigned int cvt2bf(float lo, float hi) {
  unsigned int r;
  asm volatile("v_cvt_pk_bf16_f32 %0, %1, %2" : "=v"(r) : "v"(lo), "v"(hi));
  return r;
}

__device__ __forceinline__ float sigm(float x) {
  return 1.f / (1.f + __expf(-x));
}
__device__ __forceinline__ float tanh_s(float x) {
  float a = fabsf(x);
  float e = __expf(-2.f * a);
  float r = (1.f - e) / (1.f + e);
  return x < 0.f ? -r : r;
}

// ---------- Phase 1: bf16 MFMA GEMM, fp32 inputs converted in-register ----------
// G[m][n'] = X[m][:] @ Wx[:][c(n')] + bx[c] + bh[c], stored bf16, permuted cols.
// 128x128 tile, BK=32, 4 waves (2x2 quadrants of 64x64). LDS holds bf16
// fragments in frag-major [tileIdx][lane][8] layout (conflict-free b128 reads,
// same pattern as the proven recurrence Wswz). No extra workspace.
__global__ __launch_bounds__(256) void gemm_xmfma(
    const float* __restrict__ X,
    const float* __restrict__ W0, const float* __restrict__ W1,
    const float* __restrict__ W2, const float* __restrict__ W3,
    const float* __restrict__ bx0, const float* __restrict__ bx1,
    const float* __restrict__ bx2, const float* __restrict__ bx3,
    const float* __restrict__ bh0, const float* __restrict__ bh1,
    const float* __restrict__ bh2, const float* __restrict__ bh3,
    unsigned short* __restrict__ G)
{
  // [rt|ct 0..7][aq 0..3][16-lane group][j 0..7] = 4096 ushort = 8KB each
  __shared__ __align__(16) unsigned short Afr[8 * 512];
  __shared__ __align__(16) unsigned short Bfr[8 * 512];

  const int tid  = threadIdx.x;
  const int n0   = blockIdx.x * 128;
  const int m0   = blockIdx.y * 128;
  const int lane = tid & 63;
  const int wv   = tid >> 6;
  const int wr   = wv >> 1, wc = wv & 1;   // wave quadrant
  const int ar   = lane & 15, aq = lane >> 4;

  // ---- A staging map: thread -> (row = tid>>1, half = tid&1), 16 k-consec fp32
  const int arow  = tid >> 1;
  const int ahalf = tid & 1;
  const float* ga = X + (size_t)(m0 + arow) * DIM + ahalf * 16;
  // ushort idx = (arow>>4)*512 + aq*128 + (arow&15)*8 ; aq = ahalf*2 + {0,1}
  unsigned short* la0 = &Afr[(arow >> 4) * 512 + (ahalf * 2) * 128 + (arow & 15) * 8];
  unsigned short* la1 = la0 + 128;

  // ---- B staging map: 512 slots (n'l 0..127 x aqb 0..3); thread owns tid, tid+256
  const float* gbp[2];
  unsigned short* lbp[2];
#pragma unroll
  for (int q = 0; q < 2; ++q) {
    int s = tid + q * 256;
    int nl = s >> 2, aqb = s & 3;
    int g = (nl >> 2) & 3, u = nl & 3;
    int c = (n0 >> 2) + ((nl >> 4) << 2) + u;       // source column in Wx_g
    const float* Wg = (g == 0) ? W0 : (g == 1) ? W1 : (g == 2) ? W2 : W3;
    gbp[q] = Wg + (size_t)aqb * 8 * HID + c;
    lbp[q] = &Bfr[((nl >> 4) * 4 + aqb) * 128 + (nl & 15) * 8];
  }

  floatx4 acc[4][4];
#pragma unroll
  for (int mi = 0; mi < 4; ++mi)
#pragma unroll
    for (int ni = 0; ni < 4; ++ni)
      acc[mi][ni] = (floatx4){0.f, 0.f, 0.f, 0.f};

  for (int kt = 0; kt < 32; ++kt) {
    const int k0 = kt * 32;
    // issue all global loads for this tile (overlap with other waves' MFMA)
    float4 av0 = *(const float4*)(ga + k0);
    float4 av1 = *(const float4*)(ga + k0 + 4);
    float4 av2 = *(const float4*)(ga + k0 + 8);
    float4 av3 = *(const float4*)(ga + k0 + 12);
    float fb[2][8];
#pragma unroll
    for (int q = 0; q < 2; ++q)
#pragma unroll
      for (int j = 0; j < 8; ++j)
        fb[q][j] = gbp[q][(size_t)(k0 + j) * HID];

    __syncthreads();   // all waves done reading prev tile's fragments
    {
      uint4 wa;
      wa.x = cvt2bf(av0.x, av0.y); wa.y = cvt2bf(av0.z, av0.w);
      wa.z = cvt2bf(av1.x, av1.y); wa.w = cvt2bf(av1.z, av1.w);
      *(uint4*)la0 = wa;
      wa.x = cvt2bf(av2.x, av2.y); wa.y = cvt2bf(av2.z, av2.w);
      wa.z = cvt2bf(av3.x, av3.y); wa.w = cvt2bf(av3.z, av3.w);
      *(uint4*)la1 = wa;
#pragma unroll
      for (int q = 0; q < 2; ++q) {
        uint4 wb;
        wb.x = cvt2bf(fb[q][0], fb[q][1]); wb.y = cvt2bf(fb[q][2], fb[q][3]);
        wb.z = cvt2bf(fb[q][4], fb[q][5]); wb.w = cvt2bf(fb[q][6], fb[q][7]);
        *(uint4*)lbp[q] = wb;
      }
    }
    __syncthreads();   // staging complete

    ABFrag a[4], b[4];
#pragma unroll
    for (int mi = 0; mi < 4; ++mi)
      a[mi].u = *(const uint4*)&Afr[((wr * 4 + mi) * 64 + lane) * 8];
#pragma unroll
    for (int ni = 0; ni < 4; ++ni)
      b[ni].u = *(const uint4*)&Bfr[((wc * 4 + ni) * 64 + lane) * 8];
#pragma unroll
    for (int mi = 0; mi < 4; ++mi)
#pragma unroll
      for (int ni = 0; ni < 4; ++ni)
        acc[mi][ni] = __builtin_amdgcn_mfma_f32_16x16x32_bf16(a[mi].s, b[ni].s, acc[mi][ni], 0, 0, 0);
  }

  // epilogue: fold biases (gate g is fixed per lane: g = ar>>2), store bf16 G
  const int eg = ar >> 2, eu = ar & 3;
  const float* bxp = (eg == 0) ? bx0 : (eg == 1) ? bx1 : (eg == 2) ? bx2 : bx3;
  const float* bhp = (eg == 0) ? bh0 : (eg == 1) ? bh1 : (eg == 2) ? bh2 : bh3;
  float bias[4];
#pragma unroll
  for (int ni = 0; ni < 4; ++ni) {
    int npr = n0 + wc * 64 + ni * 16 + ar;
    int c = ((npr >> 4) << 2) + eu;
    bias[ni] = bxp[c] + bhp[c];
  }
  // C layout: col = lane&15, row = (lane>>4)*4 + reg (proven)
#pragma unroll
  for (int mi = 0; mi < 4; ++mi)
#pragma unroll
    for (int ni = 0; ni < 4; ++ni)
#pragma unroll
      for (int r = 0; r < 4; ++r) {
        int grow = m0 + wr * 64 + mi * 16 + aq * 4 + r;
        int gcol = n0 + wc * 64 + ni * 16 + ar;
        G[(size_t)grow * GCOLS + gcol] = f2bf(acc[mi][ni][r] + bias[ni]);
      }
}

// ---------- Phase 2: VERBATIM round-2 (proven passing) ----------
__global__ __launch_bounds__(256) void lstm_rec(
    const unsigned short* __restrict__ G,       // [512*64][4096] bf16, permuted
    const float* __restrict__ Whf, const float* __restrict__ Whi,
    const float* __restrict__ Who, const float* __restrict__ Whc,
    unsigned short* __restrict__ hbuf,          // bf16 [2][64][1024] ping-pong
    unsigned long long* __restrict__ barCnt,    // 1 counter
    float* __restrict__ out)                    // h_seq | h | c (fp32)
{
  // [kt 32][ct 4][lane 64][8 bf16] = 128 KB B-fragments
  __shared__ __align__(16) unsigned short Wswz[32 * 4 * 64 * 8];
  __shared__ float pre[64][65];                  // preacts [batch][colInBlock]
  __shared__ __align__(8) unsigned short hout[64][16]; // h staging [batch][unit]

  const int tid  = threadIdx.x;
  const int bid  = blockIdx.x;
  const int j0   = bid * 16;      // first hidden unit owned by this block
  const int lane = tid & 63;
  const int wv   = tid >> 6;

  // One-time: swizzle 64 Wh gate-columns into MFMA B-fragment order.
  for (int idx = tid; idx < 32 * 4 * 64; idx += 256) {
    int kt = idx >> 8, ct = (idx >> 6) & 3, l = idx & 63;
    int ci = l & 15, g = ci >> 2, u = ci & 3;
    const float* W = (g==0) ? Whf : (g==1) ? Whi : (g==2) ? Who : Whc;
    int col = j0 + ct * 4 + u;
    int kbase = kt * 32 + (l >> 4) * 8;
    unsigned short* dst = &Wswz[idx * 8];
#pragma unroll
    for (int j = 0; j < 8; ++j)
      dst[j] = f2bf(W[(size_t)(kbase + j) * HID + col]);
  }
  // One-time: zero h0 stripe (slot 0): 64 rows x 4 u64 -> exactly 256 threads
  {
    int row = tid >> 2, part = tid & 3;
    unsigned long long* dst =
        (unsigned long long*)(hbuf + (size_t)row * HID + j0 + part * 4);
    __hip_atomic_store(dst, 0ull, __ATOMIC_RELAXED, __HIP_MEMORY_SCOPE_AGENT);
  }
  if (bid == 0 && tid == 0)
    __hip_atomic_store(barCnt, 0ull, __ATOMIC_RELAXED, __HIP_MEMORY_SCOPE_AGENT);

  cg::grid_group grid = cg::this_grid();
  grid.sync();   // ONLY init sync: Wswz is block-local; h0 + counter global

  const int ar = lane & 15;      // A row in tile / C col
  const int aq = lane >> 4;      // quad
  const int mrow = wv * 16 + ar; // batch row this lane loads for A
  const int pb = tid & 63;       // pointwise: batch
  const int pg = tid >> 6;       // pointwise: unit group (4 units, == B-tile ct)
  float c_reg[4] = {0.f, 0.f, 0.f, 0.f};
  unsigned long long tgt = 0;

  for (int t = 0; t < SEQ; ++t) {
    const unsigned short* hp = hbuf + (t & 1) * (BATCH * HID);
    const unsigned short* Gt = G + (size_t)t * (BATCH * GCOLS);

    // prefetch this thread's own 32B G slice (16 contiguous permuted cols:
    // units pg*4..pg*4+3 x 4 gates); consumed after the MFMA loop
    const unsigned short* gp = Gt + (size_t)pb * GCOLS + bid * 64 + pg * 16;
    uint4 gva = *(const uint4*)gp;
    uint4 gvb = *(const uint4*)(gp + 8);

    // A-fragments straight from coherent h buffer (interleaved, proven):
    // 4 x u64 agent loads per 2 K-tiles, pipelined against 8 MFMAs.
    const unsigned long long* ap =
        (const unsigned long long*)(hp + (size_t)mrow * HID);
    floatx4 acc[4][2];
#pragma unroll
    for (int ct = 0; ct < 4; ++ct) {
      acc[ct][0] = (floatx4){0.f, 0.f, 0.f, 0.f};
      acc[ct][1] = (floatx4){0.f, 0.f, 0.f, 0.f};
    }
#pragma unroll 4
    for (int kt = 0; kt < 32; kt += 2) {
      ABFrag2 a0, a1;
      a0.q[0] = __hip_atomic_load(ap + 8*kt + 2*aq,     __ATOMIC_RELAXED, __HIP_MEMORY_SCOPE_AGENT);
      a0.q[1] = __hip_atomic_load(ap + 8*kt + 2*aq + 1, __ATOMIC_RELAXED, __HIP_MEMORY_SCOPE_AGENT);
      a1.q[0] = __hip_atomic_load(ap + 8*kt + 8 + 2*aq, __ATOMIC_RELAXED, __HIP_MEMORY_SCOPE_AGENT);
      a1.q[1] = __hip_atomic_load(ap + 8*kt + 9 + 2*aq, __ATOMIC_RELAXED, __HIP_MEMORY_SCOPE_AGENT);
#pragma unroll
      for (int ct = 0; ct < 4; ++ct) {
        ABFrag b0, b1;
        b0.u = *(const uint4*)&Wswz[((kt * 4 + ct) * 64 + lane) * 8];
        b1.u = *(const uint4*)&Wswz[(((kt + 1) * 4 + ct) * 64 + lane) * 8];
        acc[ct][0] = __builtin_amdgcn_mfma_f32_16x16x32_bf16(a0.s, b0.s, acc[ct][0], 0, 0, 0);
        acc[ct][1] = __builtin_amdgcn_mfma_f32_16x16x32_bf16(a1.s, b1.s, acc[ct][1], 0, 0, 0);
      }
    }

    // C layout: col = lane&15, row = (lane>>4)*4 + reg ; row = batch-in-wave
#pragma unroll
    for (int ct = 0; ct < 4; ++ct)
#pragma unroll
      for (int r = 0; r < 4; ++r)
        pre[wv * 16 + aq * 4 + r][ct * 16 + ar] = acc[ct][0][r] + acc[ct][1][r];
    __syncthreads();

    // pointwise: thread (pb, pg) owns batch pb, units j0+pg*4 .. +3
    {
      union { uint4 u; unsigned short s[8]; } ga, gb;
      ga.u = gva; gb.u = gvb;
      float hq[4];
#pragma unroll
      for (int uu = 0; uu < 4; ++uu) {
        float pf = pre[pb][pg*16 + uu]      + bf2f(ga.s[uu]);      // gate f
        float pi = pre[pb][pg*16 + 4 + uu]  + bf2f(ga.s[4 + uu]);  // gate i
        float po = pre[pb][pg*16 + 8 + uu]  + bf2f(gb.s[uu]);      // gate o
        float pc = pre[pb][pg*16 + 12 + uu] + bf2f(gb.s[4 + uu]);  // gate c
        float f  = sigm(pf);
        float i2 = sigm(pi);
        float o  = sigm(po);
        float gg = tanh_s(pc);
        c_reg[uu] = f * c_reg[uu] + i2 * gg;
        hq[uu] = o * tanh_s(c_reg[uu]);
      }
      union { unsigned long long q; unsigned short s[4]; } hv;
#pragma unroll
      for (int uu = 0; uu < 4; ++uu) hv.s[uu] = f2bf(hq[uu]);
      *(unsigned long long*)&hout[pb][pg * 4] = hv.q;

      float4 ov = {hq[0], hq[1], hq[2], hq[3]};
      *(float4*)(out + ((size_t)t * BATCH + pb) * HID + j0 + pg * 4) = ov;
      if (t == SEQ - 1) {
        *(float4*)(out + (size_t)SEQ * BATCH * HID + (size_t)pb * HID + j0 + pg * 4) = ov;
        float4 cv = {c_reg[0], c_reg[1], c_reg[2], c_reg[3]};
        *(float4*)(out + (size_t)SEQ * BATCH * HID + (size_t)BATCH * HID
                   + (size_t)pb * HID + j0 + pg * 4) = cv;
      }
    }
    __syncthreads();

    // publish h_new: WAVE 0 ONLY, 4 u64 coherent stores per batch row
    if (tid < 64) {
      unsigned long long* dstrow = (unsigned long long*)
          (hbuf + ((t + 1) & 1) * (BATCH * HID) + (size_t)tid * HID + j0);
#pragma unroll
      for (int p = 0; p < 4; ++p) {
        unsigned long long pv = *(const unsigned long long*)&hout[tid][p * 4];
        __hip_atomic_store(dstrow + p, pv, __ATOMIC_RELAXED, __HIP_MEMORY_SCOPE_AGENT);
      }
    }
    // flush-free barrier: drain wave-0 stores to coherence point, arrive, spin
    tgt += NBLK;
    if (tid == 0) {
      asm volatile("s_waitcnt vmcnt(0)" ::: "memory");
      __hip_atomic_fetch_add(barCnt, 1ull, __ATOMIC_RELAXED, __HIP_MEMORY_SCOPE_AGENT);
      while (__hip_atomic_load(barCnt, __ATOMIC_RELAXED, __HIP_MEMORY_SCOPE_AGENT)
             < tgt)
        __builtin_amdgcn_s_sleep(1);
    }
    __syncthreads();  // releases block; next step's A-loads read L3-fresh h
  }
}

extern "C" void kernel_launch(void* const* d_in, const int* in_sizes, int n_in,
                              void* d_out, int out_size, void* d_ws, size_t ws_size,
                              hipStream_t stream)
{
  const float* x   = (const float*)d_in[0];
  const float* Wxf = (const float*)d_in[1];
  const float* bxf = (const float*)d_in[2];
  const float* Wxi = (const float*)d_in[3];
  const float* bxi = (const float*)d_in[4];
  const float* Wxo = (const float*)d_in[5];
  const float* bxo = (const float*)d_in[6];
  const float* Wxc = (const float*)d_in[7];
  const float* bxc = (const float*)d_in[8];
  const float* Whf = (const float*)d_in[9];
  const float* bhf = (const float*)d_in[10];
  const float* Whi = (const float*)d_in[11];
  const float* bhi = (const float*)d_in[12];
  const float* Who = (const float*)d_in[13];
  const float* bho = (const float*)d_in[14];
  const float* Whc = (const float*)d_in[15];
  const float* bhc = (const float*)d_in[16];

  // ws: G bf16 (256MB) | hbuf bf16 [2][64][1024] (256KB) | barrier counter
  // (byte-identical layout to the proven round-2 configuration)
  const size_t G_BYTES = (size_t)SEQ * BATCH * GCOLS * sizeof(unsigned short);
  const size_t H_BYTES = (size_t)2 * BATCH * HID * sizeof(unsigned short);
  unsigned short* G    = (unsigned short*)d_ws;
  unsigned short* hbuf = (unsigned short*)((char*)d_ws + G_BYTES);
  unsigned long long* barCnt = (unsigned long long*)((char*)d_ws + G_BYTES + H_BYTES);
  float* out = (float*)d_out;

  hipLaunchKernelGGL(gemm_xmfma, dim3(32, 256), dim3(256), 0, stream,
                     x, Wxf, Wxi, Wxo, Wxc,
                     bxf, bxi, bxo, bxc,
                     bhf, bhi, bho, bhc, G);

  void* args[] = { (void*)&G, (void*)&Whf, (void*)&Whi, (void*)&Who, (void*)&Whc,
                   (void*)&hbuf, (void*)&barCnt, (void*)&out };
  hipLaunchCooperativeKernel((void*)lstm_rec, dim3(NBLK), dim3(256), args, 0, stream);
}